// Round 2
// baseline (116.869 us; speedup 1.0000x reference)
//
#include <hip/hip_runtime.h>

// Pendulum2 DAE closed-form per-row solve.
// Row: coords = [x0 x1 x2 x3 | v0 v1 v2 v3]  ->  out = [v0..v3 | a0..a3]
// Derivation (M0=M1=G=10, Minv = 0.1*I):
//   a = x0-x2, b = x1-x3
//   L00 = 0.4(x0^2+x1^2); L01 = 0.4(x0*a + x1*b); L11 = 0.8(a^2+b^2)
//   R1  = -20*x1 + 2(v0^2+v1^2); R2 = 2((v0-v2)^2+(v1-v3)^2)
//   [L00 L01; L01 L11] lam = [R1; R2]  (2x2 Cramer, Kahan-compensated fp32)
//   acc = 0.1 * (F - phi_q^T lam), F = (0,-100,0,-100)
//
// R3: __builtin_nontemporal_* no win — reverted.
// R4: pair-shuffle coalescing (each thread owns ONE lane-contiguous float4;
//     __shfl_xor(.,1) exchanges x/v halves). 115.2 -> 112.6 us.
// R5 (this round): MLP. One load/thread = one outstanding VMEM per lane ->
//     wave stalls on vmcnt(0) immediately; BW carried only by wave-launch
//     rate across 16K tiny blocks. Now grid-stride, 2048 blocks, UNROLL=8:
//     each thread issues 8 dwordx4 loads up front (8 in flight/lane), then
//     shuffles/solves/stores. Stride = gridDim*blockDim (even), so each
//     thread's parity (x-half vs v-half) is uniform across iterations and
//     shuffle partners stay in adjacent lanes.

typedef float f32x4 __attribute__((ext_vector_type(4)));

#define UNROLL 8

// Kahan-compensated 2x2 determinant: a*d - b*c with one extra fma.
__device__ __forceinline__ float det2x2(float a, float d, float b, float c) {
  float w = b * c;
  float e = fmaf(b, c, -w);     // exact low part of b*c
  float f = fmaf(a, d, -w);     // a*d - w, single rounding
  return f - e;                 // (a*d - b*c) to ~fp64 accuracy
}

// Process one lane-contiguous float4 (even g = x-half, odd g = v-half).
// Returns the float4 that belongs at this g in the output (even -> v, odd -> a).
__device__ __forceinline__ f32x4 solve_one(f32x4 mine, bool haveX) {
  f32x4 other;
  other.x = __shfl_xor(mine.x, 1);
  other.y = __shfl_xor(mine.y, 1);
  other.z = __shfl_xor(mine.z, 1);
  other.w = __shfl_xor(mine.w, 1);

  f32x4 xv = haveX ? mine : other;    // x0 x1 x2 x3
  f32x4 vv = haveX ? other : mine;    // v0 v1 v2 v3

  float x0 = xv.x, x1 = xv.y, x2 = xv.z, x3 = xv.w;
  float v0 = vv.x, v1 = vv.y, v2 = vv.z, v3 = vv.w;

  float da = x0 - x2, db = x1 - x3;
  float dv0 = v0 - v2, dv1 = v1 - v3;

  float L00 = 0.4f * fmaf(x0, x0, x1 * x1);
  float L01 = 0.4f * fmaf(x0, da, x1 * db);
  float L11 = 0.8f * fmaf(da, da, db * db);

  float R1 = fmaf(-20.0f, x1, 2.0f * fmaf(v0, v0, v1 * v1));
  float R2 = 2.0f * fmaf(dv0, dv0, dv1 * dv1);

  // Compensated Cramer solve (handles near-singular rows without fp64).
  float det  = det2x2(L00, L11, L01, L01);
  float num1 = det2x2(L11, R1, L01, R2);
  float num2 = det2x2(L00, R2, L01, R1);
  float inv = 1.0f / det;
  float lam1 = num1 * inv;
  float lam2 = num2 * inv;

  float aR0 = -2.0f * fmaf(x0, lam1, da * lam2);
  float aR1 = fmaf(-2.0f, fmaf(x1, lam1, db * lam2), -100.0f);
  float aR2 = 2.0f * da * lam2;
  float aR3 = fmaf(2.0f * db, lam2, -100.0f);

  f32x4 av;
  av.x = 0.1f * aR0;
  av.y = 0.1f * aR1;
  av.z = 0.1f * aR2;
  av.w = 0.1f * aR3;

  return haveX ? vv : av;
}

__global__ __launch_bounds__(256) void pendulum_dae_kernel(
    const float* __restrict__ coords, float* __restrict__ out, int n4) {
  const int stride = gridDim.x * blockDim.x;  // even (multiples of 256)
  const int g0 = blockIdx.x * blockDim.x + threadIdx.x;
  const bool haveX = ((g0 & 1) == 0);  // parity uniform across iterations

  const f32x4* __restrict__ in4 = (const f32x4*)coords;
  f32x4* __restrict__ out4 = (f32x4*)out;

  if (g0 + (UNROLL - 1) * stride < n4) {
    // Fast path: all UNROLL elements in range. Issue all loads first.
    f32x4 mine[UNROLL];
#pragma unroll
    for (int j = 0; j < UNROLL; ++j) mine[j] = in4[g0 + j * stride];
#pragma unroll
    for (int j = 0; j < UNROLL; ++j) {
      out4[g0 + j * stride] = solve_one(mine[j], haveX);
    }
  } else {
    // Tail path (never taken when n4 % (grid*block*UNROLL) == 0).
    for (int j = 0; j < UNROLL; ++j) {
      int g = g0 + j * stride;
      if (g < n4) out4[g] = solve_one(in4[g], haveX);
    }
  }
}

extern "C" void kernel_launch(void* const* d_in, const int* in_sizes, int n_in,
                              void* d_out, int out_size, void* d_ws,
                              size_t ws_size, hipStream_t stream) {
  // d_in[0] = t (unused, size 1), d_in[1] = coords (bs*8 fp32)
  const float* coords = (const float*)d_in[1];
  float* out = (float*)d_out;
  int n4 = in_sizes[1] / 4;  // total float4s (2 per row)
  int block = 256;
  int per_block = block * UNROLL;
  int grid = (n4 + per_block - 1) / per_block;  // 2048 for bs = 2,097,152
  pendulum_dae_kernel<<<grid, block, 0, stream>>>(coords, out, n4);
}

// Round 3
// 112.668 us; speedup vs baseline: 1.0373x; 1.0373x over previous
//
#include <hip/hip_runtime.h>

// Pendulum2 DAE closed-form per-row solve.
// Row: coords = [x0 x1 x2 x3 | v0 v1 v2 v3]  ->  out = [v0..v3 | a0..a3]
// Derivation (M0=M1=G=10, Minv = 0.1*I):
//   a = x0-x2, b = x1-x3
//   L00 = 0.4(x0^2+x1^2); L01 = 0.4(x0*a + x1*b); L11 = 0.8(a^2+b^2)
//   R1  = -20*x1 + 2(v0^2+v1^2); R2 = 2((v0-v2)^2+(v1-v3)^2)
//   [L00 L01; L01 L11] lam = [R1; R2]  (2x2 Cramer, Kahan-compensated fp32)
//   acc = 0.1 * (F - phi_q^T lam), F = (0,-100,0,-100)
//
// R3: __builtin_nontemporal_* no win — reverted.
// R4: pair-shuffle coalescing (each thread owns ONE lane-contiguous float4;
//     __shfl_xor(.,1) swaps x/v halves). 115.2 -> 112.6 us. BEST so far.
// R5 FAILED (116.9): grid-stride UNROLL=8 put one thread's accesses 8 MiB
//     apart -> each wave touched 8 far-apart DRAM regions, grid no longer a
//     dense sweep. MLP up, DRAM page/channel locality down.
// R6 (this round): keep MLP but make it BLOCK-CONTIGUOUS (copy-ubench shape):
//     each 256-thread block owns 1024 consecutive float4s (16 KiB); thread
//     does 4 coalesced loads at tid + j*256 (4 dwordx4 in flight/lane, dense
//     front through memory). Parity (tid&1) uniform since 256 is even.

typedef float f32x4 __attribute__((ext_vector_type(4)));

#define UNROLL 4

// Kahan-compensated 2x2 determinant: a*d - b*c with one extra fma.
__device__ __forceinline__ float det2x2(float a, float d, float b, float c) {
  float w = b * c;
  float e = fmaf(b, c, -w);     // exact low part of b*c
  float f = fmaf(a, d, -w);     // a*d - w, single rounding
  return f - e;                 // (a*d - b*c) to ~fp64 accuracy
}

// Process one lane-contiguous float4 (even g = x-half, odd g = v-half).
// Returns the float4 that belongs at this g in the output (even -> v, odd -> a).
__device__ __forceinline__ f32x4 solve_one(f32x4 mine, bool haveX) {
  f32x4 other;
  other.x = __shfl_xor(mine.x, 1);
  other.y = __shfl_xor(mine.y, 1);
  other.z = __shfl_xor(mine.z, 1);
  other.w = __shfl_xor(mine.w, 1);

  f32x4 xv = haveX ? mine : other;    // x0 x1 x2 x3
  f32x4 vv = haveX ? other : mine;    // v0 v1 v2 v3

  float x0 = xv.x, x1 = xv.y, x2 = xv.z, x3 = xv.w;
  float v0 = vv.x, v1 = vv.y, v2 = vv.z, v3 = vv.w;

  float da = x0 - x2, db = x1 - x3;
  float dv0 = v0 - v2, dv1 = v1 - v3;

  float L00 = 0.4f * fmaf(x0, x0, x1 * x1);
  float L01 = 0.4f * fmaf(x0, da, x1 * db);
  float L11 = 0.8f * fmaf(da, da, db * db);

  float R1 = fmaf(-20.0f, x1, 2.0f * fmaf(v0, v0, v1 * v1));
  float R2 = 2.0f * fmaf(dv0, dv0, dv1 * dv1);

  // Compensated Cramer solve (handles near-singular rows without fp64).
  float det  = det2x2(L00, L11, L01, L01);
  float num1 = det2x2(L11, R1, L01, R2);
  float num2 = det2x2(L00, R2, L01, R1);
  float inv = 1.0f / det;
  float lam1 = num1 * inv;
  float lam2 = num2 * inv;

  float aR0 = -2.0f * fmaf(x0, lam1, da * lam2);
  float aR1 = fmaf(-2.0f, fmaf(x1, lam1, db * lam2), -100.0f);
  float aR2 = 2.0f * da * lam2;
  float aR3 = fmaf(2.0f * db, lam2, -100.0f);

  f32x4 av;
  av.x = 0.1f * aR0;
  av.y = 0.1f * aR1;
  av.z = 0.1f * aR2;
  av.w = 0.1f * aR3;

  return haveX ? vv : av;
}

__global__ __launch_bounds__(256) void pendulum_dae_kernel(
    const float* __restrict__ coords, float* __restrict__ out, int n4) {
  const int tid = threadIdx.x;
  const int base = blockIdx.x * (256 * UNROLL) + tid;  // block-contiguous chunk
  const bool haveX = ((tid & 1) == 0);  // parity uniform (256 is even)

  const f32x4* __restrict__ in4 = (const f32x4*)coords;
  f32x4* __restrict__ out4 = (f32x4*)out;

  if (base + 3 * 256 < n4) {
    // Fast path: whole chunk in range. Issue all 4 loads first (4 in flight).
    f32x4 m0 = in4[base];
    f32x4 m1 = in4[base + 256];
    f32x4 m2 = in4[base + 512];
    f32x4 m3 = in4[base + 768];
    out4[base]       = solve_one(m0, haveX);
    out4[base + 256] = solve_one(m1, haveX);
    out4[base + 512] = solve_one(m2, haveX);
    out4[base + 768] = solve_one(m3, haveX);
  } else {
    // Tail (not taken at bs=2,097,152: n4 = 4,194,304 = 4096 * 1024 exactly).
    for (int j = 0; j < UNROLL; ++j) {
      int g = base + j * 256;
      if (g < n4) out4[g] = solve_one(in4[g], haveX);
    }
  }
}

extern "C" void kernel_launch(void* const* d_in, const int* in_sizes, int n_in,
                              void* d_out, int out_size, void* d_ws,
                              size_t ws_size, hipStream_t stream) {
  // d_in[0] = t (unused, size 1), d_in[1] = coords (bs*8 fp32)
  const float* coords = (const float*)d_in[1];
  float* out = (float*)d_out;
  int n4 = in_sizes[1] / 4;  // total float4s (2 per row)
  int block = 256;
  int per_block = block * UNROLL;  // 1024 float4s = 16 KiB per block
  int grid = (n4 + per_block - 1) / per_block;  // 4096 for bs = 2,097,152
  pendulum_dae_kernel<<<grid, block, 0, stream>>>(coords, out, n4);
}